// Round 6
// baseline (574.495 us; speedup 1.0000x reference)
//
#include <hip/hip_runtime.h>
#include <math.h>

#define B_ 4
#define C_ 2048
#define E_ 1024
#define H_ 16
#define D_ 64
#define ROWS_ (B_*C_)   // 8192

typedef __bf16 bf16x8 __attribute__((ext_vector_type(8)));
typedef float f32x4 __attribute__((ext_vector_type(4)));

__device__ __forceinline__ float b2f(unsigned short u) {
  unsigned int x = ((unsigned int)u) << 16;
  return __builtin_bit_cast(float, x);
}
__device__ __forceinline__ unsigned short f2b(float f) {
  unsigned int x = __builtin_bit_cast(unsigned int, f);
  unsigned int r = (x + 0x7FFFu + ((x >> 16) & 1u)) >> 16;
  return (unsigned short)r;
}
__device__ __forceinline__ unsigned short tob(float f) { return f2b(f); }
__device__ __forceinline__ unsigned short tob(unsigned short u) { return u; }
__device__ __forceinline__ void store_out(float* p, float v) { *p = v; }
__device__ __forceinline__ void store_out(unsigned short* p, float v) { *p = f2b(v); }

__device__ __forceinline__ void async16(const void* g, void* l) {
  __builtin_amdgcn_global_load_lds(
      (__attribute__((address_space(1))) unsigned int*)g,
      (__attribute__((address_space(3))) unsigned int*)l, 16, 0, 0);
}

// ------------- 64x64 tiled transpose, InT -> bf16 ----------------------
template <typename InT>
__global__ __launch_bounds__(256) void transpose64(
    const InT* __restrict__ in, unsigned short* __restrict__ out,
    int s_in, int s_out, int Hz, long zs_b, long zs_h, long zs_out)
{
  __shared__ unsigned short t[64][65];
  int z = blockIdx.z;
  long ib = (long)(z / Hz) * zs_b + (long)(z % Hz) * zs_h;
  long ob = (long)z * zs_out;
  int r0 = blockIdx.y * 64, c0 = blockIdx.x * 64;
  int lane = threadIdx.x & 63, grp = threadIdx.x >> 6;
  for (int i = grp; i < 64; i += 4)
    t[i][lane] = tob(in[ib + (long)(r0 + i) * s_in + c0 + lane]);
  __syncthreads();
  for (int i = grp; i < 64; i += 4)
    out[ob + (long)(c0 + i) * s_out + r0 + lane] = t[lane][i];
}

__global__ void concat_bias(const float* __restrict__ q,
                            const float* __restrict__ k,
                            const float* __restrict__ v,
                            float* __restrict__ o)
{
  int i = blockIdx.x * 256 + threadIdx.x;  // 3072 total
  o[i] = (i < 1024) ? q[i] : (i < 2048) ? k[i - 1024] : v[i - 2048];
}

// ---------------- LayerNorm (optionally fused residual add) ------------
__global__ __launch_bounds__(256) void ln_kernel(
    const float* __restrict__ xin, const unsigned short* __restrict__ addend,
    const float* __restrict__ g, const float* __restrict__ beta,
    unsigned short* __restrict__ yout, float* __restrict__ out1)
{
  int row = blockIdx.x, tid = threadIdx.x;
  size_t base = (size_t)row * E_ + tid * 4;
  float4 xa = *(const float4*)(xin + base);
  float v0 = xa.x, v1 = xa.y, v2 = xa.z, v3 = xa.w;
  if (addend) {
    ushort4 aa = *(const ushort4*)(addend + base);
    v0 += b2f(aa.x); v1 += b2f(aa.y); v2 += b2f(aa.z); v3 += b2f(aa.w);
  }
  if (out1) {
    *(float4*)(out1 + base) = make_float4(v0, v1, v2, v3);
  }
  float s = v0 + v1 + v2 + v3;
  float sq = v0*v0 + v1*v1 + v2*v2 + v3*v3;
  #pragma unroll
  for (int off = 32; off >= 1; off >>= 1) {
    s  += __shfl_xor(s, off);
    sq += __shfl_xor(sq, off);
  }
  __shared__ float red[8];
  int wid = tid >> 6;
  if ((tid & 63) == 0) { red[wid] = s; red[4 + wid] = sq; }
  __syncthreads();
  s  = red[0] + red[1] + red[2] + red[3];
  sq = red[4] + red[5] + red[6] + red[7];
  float mu = s * (1.0f / E_);
  float var = sq * (1.0f / E_) - mu * mu;
  float rs = rsqrtf(var + 1e-5f);
  float4 ga = *(const float4*)(g + tid * 4);
  float4 ba = *(const float4*)(beta + tid * 4);
  ushort4 o;
  o.x = f2b((v0 - mu) * rs * ga.x + ba.x);
  o.y = f2b((v1 - mu) * rs * ga.y + ba.y);
  o.z = f2b((v2 - mu) * rs * ga.z + ba.z);
  o.w = f2b((v3 - mu) * rs * ga.w + ba.w);
  *(ushort4*)(yout + base) = o;
}

// ======== 256x256 BK=64 1-barrier/tile compiler-pipelined GEMM =========
// C = A @ Bt^T (+bias)(+relu)(+resid on z==0).  BM=BN=256, BK=64,
// 8 waves (2M x 4N), per-wave 128x64 out (acc[8][4] f32x4 = 128 AGPR).
// LDS 128 KiB: As/Bs[2][256*64] double-buffered on tile parity.
// R5 analysis: MFMA pipe ~2048cy/tile == LDS pipe ~2048cy/tile, but
// measured 8000cy/tile @ MfmaUtil 25% -> pipes serialized by the forced
// per-phase lgkmcnt(0) (R4) / phase sched_barriers (R3).  Fix: NO asm
// lgkm waits.  Reads issued in consumption order, MFMA clusters follow,
// sched_barrier(0) only at cluster boundaries; hipcc inserts its own
// minimal counted lgkmcnt (m97 behavior: lgkm(4/3/1/0)) so each 16-MFMA
// cluster hides the 4-8 ds_reads in flight behind it.  One cold LDS ramp
// per tile (b0/a0) instead of four.
// Hazards (1 barrier/tile): stage(t+1)->buf^1 at tile top; buf^1's last
// readers ran in tile t-1, their reads complete before their C3 MFMA
// (data dep) which precedes the t-1 end barrier -> WAR safe.  vmcnt(0)
// at tile end waits on stage issued a full tile (~2000cy) earlier >= HBM
// latency -> ~free; barrier then publishes buf^1 for t+1.
// LDS geometry: row stride 128 B, 8x16B slots, XOR(row&7) swizzle
// (measured SQ_LDS_BANK_CONFLICT == 0).  Per-element K-accum order
// unchanged from R3/R4 (mh0k0, mh1k0, mh0k1, mh1k1) -> bit-identical.
#define BARC() { asm volatile("" ::: "memory"); __builtin_amdgcn_s_barrier(); asm volatile("" ::: "memory"); }
#define SB0() __builtin_amdgcn_sched_barrier(0)

#define MFMA16(mh, AF, BF) do {                                             \
  __builtin_amdgcn_s_setprio(1);                                            \
  _Pragma("unroll")                                                         \
  for (int mt_ = 0; mt_ < 4; ++mt_)                                         \
    _Pragma("unroll")                                                       \
    for (int nt_ = 0; nt_ < 4; ++nt_)                                       \
      acc[(mh)*4+mt_][nt_] = __builtin_amdgcn_mfma_f32_16x16x32_bf16(       \
          AF[mt_], BF[nt_], acc[(mh)*4+mt_][nt_], 0, 0, 0);                 \
  __builtin_amdgcn_s_setprio(0);                                            \
} while (0)

template <typename OutT>
__global__ __launch_bounds__(512, 2) void gemm256(
    const unsigned short* __restrict__ A, const unsigned short* __restrict__ Bt,
    const float* __restrict__ bias, const float* __restrict__ resid,
    OutT* __restrict__ Co, int M, int N, int K, int lda, int ldb,
    int relu, size_t zs)
{
  __shared__ __align__(16) unsigned short As[2][256 * 64];   // 32 KiB each
  __shared__ __align__(16) unsigned short Bs[2][256 * 64];
  int tid = threadIdx.x, lane = tid & 63, wid = tid >> 6;
  int lane15 = lane & 15, quad = lane >> 4;
  int wm = wid >> 2, wn = wid & 3;

  // XCD-chunked block swizzle (M/256 == 32 assumed)
  int i = blockIdx.x;
  int xcd = i & 7, c = i >> 3;
  int bm = xcd * 4 + (c & 3);
  int bn = c >> 2;
  size_t koff = (size_t)blockIdx.z * K;
  int z0 = (blockIdx.z == 0);
  Co += (size_t)blockIdx.z * zs;

  // staging map: thread -> (row sr 0..63 per 64-row chunk, slot sc 0..7)
  // LDS dest linear (tid*16B within chunk); global col pre-swizzled.
  int sr = tid >> 3, sc = tid & 7;
  int gcol = (sc ^ (sr & 7)) * 8;                // ushort col in 64-wide tile
  const unsigned short* Ag = A + koff + (size_t)(bm * 256 + sr) * lda + gcol;
  const unsigned short* Bg = Bt + koff + (size_t)(bn * 256 + sr) * ldb + gcol;
  int dst = tid * 8;                             // ushorts (16B/thread)

  int NT = K >> 6;                               // 64-wide K tiles

  f32x4 acc[8][4];
  #pragma unroll
  for (int m = 0; m < 8; ++m)
    #pragma unroll
    for (int n = 0; n < 4; ++n) acc[m][n] = 0.0f;

  auto stage = [&](int kt) {
    unsigned short* Ad = &As[kt & 1][0] + dst;
    unsigned short* Bd = &Bs[kt & 1][0] + dst;
    const unsigned short* Asrc = Ag + kt * 64;
    const unsigned short* Bsrc = Bg + kt * 64;
    #pragma unroll
    for (int h = 0; h < 4; ++h) {
      async16(Asrc + (size_t)(h * 64) * lda, Ad + h * 4096);
      async16(Bsrc + (size_t)(h * 64) * ldb, Bd + h * 4096);
    }
  };
  int rsw = lane15 & 7;
  auto ldA = [&](const unsigned short* Ab, int mh, int m, int kk) {
    return *(const bf16x8*)&Ab[(wm * 128 + mh * 64 + m * 16 + lane15) * 64
                               + (((kk * 4 + quad) ^ rsw) * 8)];
  };
  auto ldB = [&](const unsigned short* Bb, int n, int kk) {
    return *(const bf16x8*)&Bb[(wn * 64 + n * 16 + lane15) * 64
                               + (((kk * 4 + quad) ^ rsw) * 8)];
  };

  // prologue: tile 0 staged and landed
  stage(0);
  asm volatile("s_waitcnt vmcnt(0)" ::: "memory");
  __builtin_amdgcn_s_barrier();

  #pragma unroll 1
  for (int t = 0; t < NT; ++t) {
    const unsigned short* Ab = &As[t & 1][0];
    const unsigned short* Bb = &Bs[t & 1][0];
    if (t + 1 < NT) stage(t + 1);
    bf16x8 b0[4], b1[4], a0[4], a1[4], a2[4], a3[4];
    // reads in consumption order; compiler inserts counted lgkm waits
    #pragma unroll
    for (int n = 0; n < 4; ++n) b0[n] = ldB(Bb, n, 0);
    #pragma unroll
    for (int m = 0; m < 4; ++m) a0[m] = ldA(Ab, 0, m, 0);
    #pragma unroll
    for (int m = 0; m < 4; ++m) a1[m] = ldA(Ab, 1, m, 0);
    SB0();
    MFMA16(0, a0, b0);        // hides a1's 4 reads
    SB0();
    #pragma unroll
    for (int n = 0; n < 4; ++n) b1[n] = ldB(Bb, n, 1);
    #pragma unroll
    for (int m = 0; m < 4; ++m) a2[m] = ldA(Ab, 0, m, 1);
    SB0();
    MFMA16(1, a1, b0);        // hides b1+a2's 8 reads
    SB0();
    #pragma unroll
    for (int m = 0; m < 4; ++m) a3[m] = ldA(Ab, 1, m, 1);
    SB0();
    MFMA16(0, a2, b1);        // hides a3's 4 reads
    SB0();
    MFMA16(1, a3, b1);
    // stage loads aged one full tile (>= HBM latency) -> ~free wait
    asm volatile("s_waitcnt vmcnt(0)" ::: "memory");
    BARC();
  }

  #pragma unroll
  for (int nt = 0; nt < 4; ++nt) {
    int col = bn * 256 + wn * 64 + nt * 16 + lane15;
    float bv = (bias && z0) ? bias[col] : 0.0f;
    #pragma unroll
    for (int mt = 0; mt < 8; ++mt) {
      int row0 = bm * 256 + wm * 128 + mt * 16 + quad * 4;
      #pragma unroll
      for (int r = 0; r < 4; ++r) {
        float val = acc[mt][nt][r] + bv;
        if (relu) val = fmaxf(val, 0.0f);
        if (resid && z0) val += resid[(size_t)(row0 + r) * N + col];
        store_out(&Co[(size_t)(row0 + r) * N + col], val);
      }
    }
  }
}

// ---- split-K combine: out = p0 + p1 (bias/resid folded into z=0) ------
__global__ __launch_bounds__(256) void add2(
    const float* __restrict__ p0, const float* __restrict__ p1,
    float* __restrict__ out)
{
  size_t i = ((size_t)blockIdx.x * 256 + threadIdx.x) * 4;
  float4 a = *(const float4*)(p0 + i);
  float4 b = *(const float4*)(p1 + i);
  *(float4*)(out + i) = make_float4(a.x + b.x, a.y + b.y, a.z + b.z, a.w + b.w);
}

// -------- MFMA flash attention v6 (v5 + double-buffered K/V) -----------
// Block = 128 Q rows of one head (8 waves x 16 rows, 512 threads).
// No-max softmax in log2 domain -> partials over disjoint key ranges
// combine exactly by addition.  qblk >= 8 split into two key-range halves.
// v6: K/V LDS double-buffered; counted vmcnt(2) + raw barriers.
__global__ __launch_bounds__(512) void attn_kernel(
    const unsigned short* __restrict__ qkv, const unsigned short* __restrict__ vt,
    unsigned short* __restrict__ attnb,
    float* __restrict__ opart0, float* __restrict__ opart1,
    float* __restrict__ lpart)
{
  __shared__ __align__(16) unsigned short Klds[2][64 * 64];   // [key][d]
  __shared__ __align__(16) unsigned short Vlds[2][64 * 64];   // [d][key]
  __shared__ __align__(16) unsigned short Plds[8][16 * 72];
  int tid = threadIdx.x, lane = tid & 63, widx = tid >> 6;
  int lane15 = lane & 15, quad = lane >> 4;

  int bx = blockIdx.x;
  int qblk, p, split;
  if (bx < 16) { qblk = 15 - (bx >> 1); p = bx & 1; split = 1; }
  else         { qblk = 23 - bx;        p = 0;      split = 0; }
  int ntiles = 2 * qblk + 2;
  int kt0 = (split && p) ? (qblk + 1) : 0;
  int kt1 = (split && !p) ? (qblk + 1) : ntiles;

  int bh = blockIdx.y;                   // 0..63
  int b = bh >> 4, h = bh & 15;
  int q0w = qblk * 128 + widx * 16;      // this wave's first Q row

  const float QSCALE = 0.18033688011112042f;  // 0.125 / ln(2)
  const unsigned short* qb = qkv + (size_t)(b * C_ + q0w + lane15) * 3072 + h * 64;
  bf16x8 qa0 = *(const bf16x8*)(qb + quad * 8);
  bf16x8 qa1 = *(const bf16x8*)(qb + 32 + quad * 8);
  #pragma unroll
  for (int j = 0; j < 8; ++j) {
    qa0[j] = (__bf16)((float)qa0[j] * QSCALE);
    qa1[j] = (__bf16)((float)qa1[j] * QSCALE);
  }

  float lsum[4];
  f32x4 o[4];
  #pragma unroll
  for (int r = 0; r < 4; ++r) lsum[r] = 0.0f;
  #pragma unroll
  for (int nt = 0; nt < 4; ++nt) o[nt] = 0.0f;

  int sr = tid >> 3, sc = tid & 7, sw = sr & 7;
  const unsigned short* kg = qkv + (size_t)(b * C_ + kt0 * 64 + sr) * 3072 + 1024 + h * 64 + (sc ^ sw) * 8;
  const unsigned short* vg = vt + (size_t)bh * 64 * 2048 + (size_t)sr * 2048 + (sc ^ sw) * 8 + kt0 * 64;
  unsigned short* kl = &Klds[0][sr * 64 + sc * 8];
  unsigned short* vl = &Vlds[0][sr * 64 + sc * 8];
  int swr = lane15 & 7;

  // prologue: stage tile kt0 into buf0
  async16(kg, kl);
  async16(vg, vl);
  kg += (size_t)64 * 3072;
  vg += 64;

  for (int kt = kt0; kt < kt1; ++kt) {
    int cur = (kt - kt0) & 1;
    int k0 = kt * 64;
    bool morek = (kt + 1 < kt1);
    if (morek) {
      async16(kg, kl + (cur ^ 1) * 4096);
      async16(vg, vl + (cur ^ 1) * 4096);
      kg += (size_t)64 * 3072;
      vg += 64;
      asm volatile("s_waitcnt vmcnt(2)" ::: "memory");
    } else {
      asm volatile("s_waitcnt vmcnt(0)" ::: "memory");
    }
    __builtin_amdgcn_s_barrier();
    asm volatile("" ::: "memory");

    if (k0 <= q0w + 15) {
      f32x4 s[4];
      #pragma unroll
      for (int g = 0; g < 4; ++g) s[g] = 0.0f;
      #pragma unroll
      for (int g = 0; g < 4; ++g) {
        int row = g * 16 + lane15;
        bf16x8 kf0 = *(const bf16x8*)&Klds[cur][row * 64 + ((quad ^ swr) * 8)];
        bf16x8 kf1 = *(const bf16x8*)&Klds[cur][row * 64 + (((4 + quad) ^ swr) * 8)];
        s[g] = __builtin_amdgcn_mfma_f32_16x16x32_bf16(qa0, kf0, s[g], 0, 0, 0);
        s[g] = __builtin_amdgcn_mfma_f32_16x16x32_bf16(qa1, kf1, s[g], 0, 0, 0);
      }

      if (k0 + 63 > q0w) {
        #pragma unroll
        for (int g = 0; g < 4; ++g)
          #pragma unroll
          for (int r = 0; r < 4; ++r)
            if (k0 + g * 16 + lane15 > q0w + quad * 4 + r) s[g][r] = -3.0e38f;
      }

      float pv[4][4];
      #pragma unroll
      for (int g = 0; g < 4; ++g)
        #pragma unroll
        for (int r = 0; r < 4; ++r) pv[g][r] = exp2f(s[g][r]);
      #pragma unroll
      for (int r = 0; r < 4; ++r)
        lsum[r] += (pv[0][r] + pv[1][r]) + (pv[2][r] + pv[3][r]);

      __bf16* prow = (__bf16*)&Plds[widx][0];
      #pragma unroll
      for (int g = 0; g < 4; ++g)
        #pragma unroll
        for (int r = 0; r < 4; ++r)
          prow[(quad * 4 + r) * 72 + g * 16 + lane15] = (__bf16)pv[g][r];
      asm volatile("s_waitcnt lgkmcnt(0)" ::: "memory");
      bf16x8 pa0 = *(const bf16x8*)&Plds[widx][lane15 * 72 + quad * 8];
      bf16x8 pa1 = *(const bf16x8*)&Plds[widx][lane15 * 72 + 32 + quad * 8];

      #pragma unroll
      for (int nt = 0; nt < 4; ++nt) {
        int d = nt * 16 + lane15;
        bf16x8 vf0 = *(const bf16x8*)&Vlds[cur][d * 64 + ((quad ^ swr) * 8)];
        bf16x8 vf1 = *(const bf16x8*)&Vlds[cur][d * 64 + (((4 + quad) ^ swr) * 8)];
        o[nt] = __builtin_amdgcn_mfma_f32_16x16x32_bf16(pa0, vf0, o[nt], 0, 0, 0);
        o[nt] = __builtin_amdgcn_mfma_f32_16x16x32_bf16(pa1, vf1, o[nt], 0, 0, 0);
      }
    }
    asm volatile("" ::: "memory");
    __builtin_amdgcn_s_barrier();
    asm volatile("" ::: "memory");
  }

  #pragma unroll
  for (int off = 1; off <= 8; off <<= 1)
    #pragma unroll
    for (int r = 0; r < 4; ++r)
      lsum[r] += __shfl_xor(lsum[r], off);

  if (!split) {
    float rl[4];
    #pragma unroll
    for (int r = 0; r < 4; ++r) rl[r] = 1.0f / lsum[r];
    #pragma unroll
    for (int nt = 0; nt < 4; ++nt)
      #pragma unroll
      for (int r = 0; r < 4; ++r) {
        float val = o[nt][r] * rl[r];
        attnb[(size_t)(b * C_ + q0w + quad * 4 + r) * E_ + h * 64 + nt * 16 + lane15] = f2b(val);
      }
  } else {
    float* op = p ? opart1 : opart0;
    size_t rbase = (size_t)bh * 1024 + (q0w - 1024) + quad * 4;
    #pragma unroll
    for (int nt = 0; nt < 4; ++nt)
      #pragma unroll
      for (int r = 0; r < 4; ++r)
        op[(rbase + r) * 64 + nt * 16 + lane15] = o[nt][r];
    if (lane15 == 0) {
      float* lp = lpart + (size_t)p * 65536;
      #pragma unroll
      for (int r = 0; r < 4; ++r) lp[rbase + r] = lsum[r];
    }
  }
}

// combine split-attention partials: attnb = (O0+O1)/(l0+l1) for rows 1024+
__global__ __launch_bounds__(256) void attn_combine(
    const float* __restrict__ opart0, const float* __restrict__ opart1,
    const float* __restrict__ lpart, unsigned short* __restrict__ attnb)
{
  size_t i = (size_t)blockIdx.x * 256 + threadIdx.x;  // over 64*1024*64
  int d = (int)(i & 63);
  size_t rowi = i >> 6;                 // bh*1024 + row
  int bh = (int)(rowi >> 10), row = (int)(rowi & 1023);
  float ov = opart0[rowi * 64 + d] + opart1[rowi * 64 + d];
  float lv = lpart[rowi] + lpart[65536 + rowi];
  int b = bh >> 4, h = bh & 15;
  attnb[(size_t)(b * C_ + 1024 + row) * E_ + h * 64 + d] = f2b(ov / lv);
}

// ---------------------------- launcher ---------------------------------
extern "C" void kernel_launch(void* const* d_in, const int* in_sizes, int n_in,
                              void* d_out, int out_size, void* d_ws, size_t ws_size,
                              hipStream_t stream)
{
  const float* x   = (const float*)d_in[0];
  const float* Wq  = (const float*)d_in[1];
  const float* bq  = (const float*)d_in[2];
  const float* Wk  = (const float*)d_in[3];
  const float* bk  = (const float*)d_in[4];
  const float* Wv  = (const float*)d_in[5];
  const float* bv  = (const float*)d_in[6];
  const float* g1  = (const float*)d_in[7];
  const float* be1 = (const float*)d_in[8];
  const float* g2  = (const float*)d_in[9];
  const float* be2 = (const float*)d_in[10];
  const float* W1  = (const float*)d_in[11];
  const float* bm1 = (const float*)d_in[12];
  const float* W2  = (const float*)d_in[13];
  const float* bm2 = (const float*)d_in[14];

  char* ws = (char*)d_ws;
  // Region lifetime plan:
  //  [0,16M)      norm1 (LN1 out, dead after QKV gemm) -> lpart during attn
  //               -> norm2 (LN2 out) -> overlaid by part0 at MLP2
  //  [123.7M,+32M) free during attn -> opart1 -> out1 (LN2) 
  //  [165.7M,+32M) free during attn -> opart0 -> part1 (MLP2 z1)
  float*          part0 = (float*)(ws + 0);                   // 32 MB fp32 [8192][1024]
  unsigned short* norm1 = (unsigned short*)(ws + 0);          // 16 MB bf16 (reused as norm2)
  unsigned short* wT    = (unsigned short*)(ws + 16777216);   // 6 MB  bf16 WqkvT [3072][1024]
  unsigned short* w1T   = (unsigned short*)(ws + 23068672);   // 8 MB  bf16 [4096][1024]
  float*          biasq = (float*)(ws + 39845888);            // 12 KB fp32 [3072]
  unsigned short* qkv   = (unsigned short*)(ws + 39858176);   // 48 MB bf16 [8192][3072]
  unsigned short* vtb   = (unsigned short*)(ws + 90189824);   // 16 MB bf16 [64][64][2048]
  unsigned short* mid   = (unsigned short*)(ws + 39858176);   // 64 MB bf16 [8192][4096] (aliases qkv+vtb)
  unsigned short* attnb = (unsigned short*)(ws + 106967040);  // 16 MB bf16 [8192][1024]
  float*          out1  = (float*)(ws + 123744256);           // 32 MB fp32 [8192][1024]
  unsigned short* w2T   = (unsigned short*)(ws + 157298688);  // 8 MB  bf16 [1024][4096]
  float*          part1 = (float*)(ws + 165687296);           // 32 MB fp32 [8192][1024]
  // attn split partials (dead-region overlays, see plan above):
  float*          opart0 = (float*)(ws + 165687296);          // 16.78 MB
  float*          opart1 = (float*)(ws + 123744256);          // 16.78 MB
  float*          lpartb = (float*)(ws + 0);                  // 0.5 MB
  // total: 199,241,728 bytes
  size_t part_zs = ((size_t)165687296) / 4;                   // part1 - part0 in floats

  // weight transposes (+fp32->bf16 convert) -> [N][K]
  transpose64<float><<<dim3(16, 16, 1), 256, 0, stream>>>(Wq, wT,               1024, 1024, 1, 0, 0, 0);
  transpose64<float><<<dim3(16, 16, 1), 256, 0, stream>>>(Wk, wT + 1024 * 1024, 1024, 1024, 1, 0, 0, 0);
  transpose64<float><<<dim3(16, 16, 1), 256, 0, stream>>>(Wv, wT + 2048 * 1024, 1024, 1024, 1, 0, 0, 0);
  transpose64<float><<<dim3(64, 16, 1), 256, 0, stream>>>(W1, w1T, 4096, 1024, 1, 0, 0, 0);
  transpose64<float><<<dim3(16, 64, 1), 256, 0, stream>>>(W2, w2T, 1024, 4096, 1, 0, 0, 0);
  concat_bias<<<12, 256, 0, stream>>>(bq, bk, bv, biasq);

  // LN1: norm1 = LN(x) in bf16
  ln_kernel<<<ROWS_, 256, 0, stream>>>(x, nullptr, g1, be1, norm1, nullptr);

  // fused QKV GEMM: [8192][1024] @ [3072][1024]^T -> [8192][3072] bf16
  // grid = 32 M-blocks x 12 N-blocks = 384
  gemm256<unsigned short><<<dim3(384, 1, 1), 512, 0, stream>>>(
      norm1, wT, biasq, nullptr, qkv, 8192, 3072, 1024, 1024, 1024, 0, 0);

  // V^T per head: vt[b*H+h][d][c]
  transpose64<unsigned short><<<dim3(1, 32, 64), 256, 0, stream>>>(
      qkv + 2048, vtb, 3072, 2048, 16, (long)C_ * 3072, 64, (long)64 * 2048);

  // causal flash attention v6 (split heavy qblks, dbuf K/V)
  attn_kernel<<<dim3(24, 64), 512, 0, stream>>>(qkv, vtb, attnb, opart0, opart1, lpartb);
  attn_combine<<<16384, 256, 0, stream>>>(opart0, opart1, lpartb, attnb);

  // out1 = x + attn (fp32) ; norm2 = LN(out1) bf16
  ln_kernel<<<ROWS_, 256, 0, stream>>>(x, attnb, g2, be2, norm1, out1);

  // MLP1: relu(norm2 @ W1^T + bm1) -> mid bf16  (grid 32x16 = 512)
  gemm256<unsigned short><<<dim3(512, 1, 1), 512, 0, stream>>>(
      norm1, w1T, bm1, nullptr, mid, 8192, 4096, 1024, 1024, 1024, 1, 0);

  // MLP2 split-K: z=0 adds bm2+out1, z=1 raw partial (grid 32x4 x2)
  gemm256<float><<<dim3(128, 1, 2), 512, 0, stream>>>(
      mid, w2T, bm2, out1, part0, 8192, 1024, 2048, 4096, 4096, 0, part_zs);
  // out = part0 + part1
  add2<<<8192, 256, 0, stream>>>(part0, part1, (float*)d_out);
}

// Round 7
// 566.505 us; speedup vs baseline: 1.0141x; 1.0141x over previous
//
#include <hip/hip_runtime.h>
#include <math.h>

#define B_ 4
#define C_ 2048
#define E_ 1024
#define H_ 16
#define D_ 64
#define ROWS_ (B_*C_)   // 8192

typedef __bf16 bf16x8 __attribute__((ext_vector_type(8)));
typedef float f32x4 __attribute__((ext_vector_type(4)));

__device__ __forceinline__ float b2f(unsigned short u) {
  unsigned int x = ((unsigned int)u) << 16;
  return __builtin_bit_cast(float, x);
}
__device__ __forceinline__ unsigned short f2b(float f) {
  unsigned int x = __builtin_bit_cast(unsigned int, f);
  unsigned int r = (x + 0x7FFFu + ((x >> 16) & 1u)) >> 16;
  return (unsigned short)r;
}
__device__ __forceinline__ unsigned short tob(float f) { return f2b(f); }
__device__ __forceinline__ unsigned short tob(unsigned short u) { return u; }
__device__ __forceinline__ void store_out(float* p, float v) { *p = v; }
__device__ __forceinline__ void store_out(unsigned short* p, float v) { *p = f2b(v); }

__device__ __forceinline__ void async16(const void* g, void* l) {
  __builtin_amdgcn_global_load_lds(
      (__attribute__((address_space(1))) unsigned int*)g,
      (__attribute__((address_space(3))) unsigned int*)l, 16, 0, 0);
}

// ------------- 64x64 tiled transpose, InT -> bf16 ----------------------
template <typename InT>
__global__ __launch_bounds__(256) void transpose64(
    const InT* __restrict__ in, unsigned short* __restrict__ out,
    int s_in, int s_out, int Hz, long zs_b, long zs_h, long zs_out)
{
  __shared__ unsigned short t[64][65];
  int z = blockIdx.z;
  long ib = (long)(z / Hz) * zs_b + (long)(z % Hz) * zs_h;
  long ob = (long)z * zs_out;
  int r0 = blockIdx.y * 64, c0 = blockIdx.x * 64;
  int lane = threadIdx.x & 63, grp = threadIdx.x >> 6;
  for (int i = grp; i < 64; i += 4)
    t[i][lane] = tob(in[ib + (long)(r0 + i) * s_in + c0 + lane]);
  __syncthreads();
  for (int i = grp; i < 64; i += 4)
    out[ob + (long)(c0 + i) * s_out + r0 + lane] = t[lane][i];
}

__global__ void concat_bias(const float* __restrict__ q,
                            const float* __restrict__ k,
                            const float* __restrict__ v,
                            float* __restrict__ o)
{
  int i = blockIdx.x * 256 + threadIdx.x;  // 3072 total
  o[i] = (i < 1024) ? q[i] : (i < 2048) ? k[i - 1024] : v[i - 2048];
}

// ---------------- LayerNorm (optionally fused residual add) ------------
__global__ __launch_bounds__(256) void ln_kernel(
    const float* __restrict__ xin, const unsigned short* __restrict__ addend,
    const float* __restrict__ g, const float* __restrict__ beta,
    unsigned short* __restrict__ yout, float* __restrict__ out1)
{
  int row = blockIdx.x, tid = threadIdx.x;
  size_t base = (size_t)row * E_ + tid * 4;
  float4 xa = *(const float4*)(xin + base);
  float v0 = xa.x, v1 = xa.y, v2 = xa.z, v3 = xa.w;
  if (addend) {
    ushort4 aa = *(const ushort4*)(addend + base);
    v0 += b2f(aa.x); v1 += b2f(aa.y); v2 += b2f(aa.z); v3 += b2f(aa.w);
  }
  if (out1) {
    *(float4*)(out1 + base) = make_float4(v0, v1, v2, v3);
  }
  float s = v0 + v1 + v2 + v3;
  float sq = v0*v0 + v1*v1 + v2*v2 + v3*v3;
  #pragma unroll
  for (int off = 32; off >= 1; off >>= 1) {
    s  += __shfl_xor(s, off);
    sq += __shfl_xor(sq, off);
  }
  __shared__ float red[8];
  int wid = tid >> 6;
  if ((tid & 63) == 0) { red[wid] = s; red[4 + wid] = sq; }
  __syncthreads();
  s  = red[0] + red[1] + red[2] + red[3];
  sq = red[4] + red[5] + red[6] + red[7];
  float mu = s * (1.0f / E_);
  float var = sq * (1.0f / E_) - mu * mu;
  float rs = rsqrtf(var + 1e-5f);
  float4 ga = *(const float4*)(g + tid * 4);
  float4 ba = *(const float4*)(beta + tid * 4);
  ushort4 o;
  o.x = f2b((v0 - mu) * rs * ga.x + ba.x);
  o.y = f2b((v1 - mu) * rs * ga.y + ba.y);
  o.z = f2b((v2 - mu) * rs * ga.z + ba.z);
  o.w = f2b((v3 - mu) * rs * ga.w + ba.w);
  *(ushort4*)(yout + base) = o;
}

// ============ 256x256 BK=64 8-phase bf16 GEMM (R4, frozen) =============
// Best of 5 schedule structures tried (all 620-650 TF; reg-bound
// 1-block/CU floor, see journal R6).  Do not re-tune the schedule.
#define BARC() { asm volatile("" ::: "memory"); __builtin_amdgcn_s_barrier(); asm volatile("" ::: "memory"); }
#define WAITL() { asm volatile("s_waitcnt lgkmcnt(0)" ::: "memory"); __builtin_amdgcn_sched_barrier(0); }

#define MFMA16(mh, BF) do {                                                 \
  __builtin_amdgcn_s_setprio(1);                                            \
  _Pragma("unroll")                                                         \
  for (int mt_ = 0; mt_ < 4; ++mt_)                                         \
    _Pragma("unroll")                                                       \
    for (int nt_ = 0; nt_ < 4; ++nt_)                                       \
      acc[(mh)*4+mt_][nt_] = __builtin_amdgcn_mfma_f32_16x16x32_bf16(       \
          af[mt_], BF[nt_], acc[(mh)*4+mt_][nt_], 0, 0, 0);                 \
  __builtin_amdgcn_s_setprio(0);                                            \
} while (0)

template <typename OutT>
__global__ __launch_bounds__(512, 2) void gemm256(
    const unsigned short* __restrict__ A, const unsigned short* __restrict__ Bt,
    const float* __restrict__ bias, const float* __restrict__ resid,
    OutT* __restrict__ Co, int M, int N, int K, int lda, int ldb,
    int relu, size_t zs)
{
  __shared__ __align__(16) unsigned short As[2][256 * 64];   // 32 KiB each
  __shared__ __align__(16) unsigned short Bs[2][256 * 64];
  int tid = threadIdx.x, lane = tid & 63, wid = tid >> 6;
  int lane15 = lane & 15, quad = lane >> 4;
  int wm = wid >> 2, wn = wid & 3;

  // XCD-chunked block swizzle (M/256 == 32 assumed)
  int i = blockIdx.x;
  int xcd = i & 7, c = i >> 3;
  int bm = xcd * 4 + (c & 3);
  int bn = c >> 2;
  size_t koff = (size_t)blockIdx.z * K;
  int z0 = (blockIdx.z == 0);
  Co += (size_t)blockIdx.z * zs;

  // staging map: thread -> (row sr 0..63 per 64-row chunk, slot sc 0..7)
  // LDS dest linear (tid*16B within chunk); global col pre-swizzled.
  int sr = tid >> 3, sc = tid & 7;
  int gcol = (sc ^ (sr & 7)) * 8;                // ushort col in 64-wide tile
  const unsigned short* Ag = A + koff + (size_t)(bm * 256 + sr) * lda + gcol;
  const unsigned short* Bg = Bt + koff + (size_t)(bn * 256 + sr) * ldb + gcol;
  int dst = tid * 8;                             // ushorts (16B/thread)

  int NT = K >> 6;                               // 64-wide K tiles (even)

  f32x4 acc[8][4];
  #pragma unroll
  for (int m = 0; m < 8; ++m)
    #pragma unroll
    for (int n = 0; n < 4; ++n) acc[m][n] = 0.0f;

  // stage one 128-row half (2 x global_load_lds) of A or B for tile kt
  auto stA = [&](int kt, int h) {
    const unsigned short* s = Ag + (size_t)(h * 128) * lda + kt * 64;
    unsigned short* d = &As[kt & 1][h * 8192] + dst;
    async16(s, d);
    async16(s + (size_t)64 * lda, d + 4096);
  };
  auto stB = [&](int kt, int h) {
    const unsigned short* s = Bg + (size_t)(h * 128) * ldb + kt * 64;
    unsigned short* d = &Bs[kt & 1][h * 8192] + dst;
    async16(s, d);
    async16(s + (size_t)64 * ldb, d + 4096);
  };
  int rsw = lane15 & 7;
  auto ldA = [&](int q, int mh, int m, int kk) {
    return *(const bf16x8*)&As[q][(wm * 128 + mh * 64 + m * 16 + lane15) * 64
                                  + (((kk * 4 + quad) ^ rsw) * 8)];
  };
  auto ldB = [&](int q, int n, int kk) {
    return *(const bf16x8*)&Bs[q][(wn * 64 + n * 16 + lane15) * 64
                                  + (((kk * 4 + quad) ^ rsw) * 8)];
  };

  // prologue: t0 complete (8 loads) + t1.B (4 loads); retire t0, keep t1.B
  stB(0, 0); stB(0, 1); stA(0, 0); stA(0, 1);
  stB(1, 0); stB(1, 1);
  asm volatile("s_waitcnt vmcnt(4)" ::: "memory");
  __builtin_amdgcn_s_barrier();

  #pragma unroll 1
  for (int it = 0; it < (NT >> 1); ++it) {
    int u = 2 * it;
    bool more = (u + 2 < NT);
    bf16x8 af[4], b0[4], b1[4];

    // ================= tile u (buf0) =================
    #pragma unroll
    for (int n = 0; n < 4; ++n) b0[n] = ldB(0, n, 0);
    #pragma unroll
    for (int n = 0; n < 4; ++n) b1[n] = ldB(0, n, 1);
    #pragma unroll
    for (int m = 0; m < 4; ++m) af[m] = ldA(0, 0, m, 0);
    stA(u + 1, 0);
    BARC(); WAITL();
    MFMA16(0, b0);
    BARC();
    #pragma unroll
    for (int m = 0; m < 4; ++m) af[m] = ldA(0, 1, m, 0);
    stA(u + 1, 1);
    BARC(); WAITL();
    MFMA16(1, b0);
    BARC();
    #pragma unroll
    for (int m = 0; m < 4; ++m) af[m] = ldA(0, 0, m, 1);
    if (more) stB(u + 2, 0);
    BARC(); WAITL();
    MFMA16(0, b1);
    BARC();
    #pragma unroll
    for (int m = 0; m < 4; ++m) af[m] = ldA(0, 1, m, 1);
    if (more) stB(u + 2, 1);
    BARC(); WAITL();
    MFMA16(1, b1);
    if (more) { asm volatile("s_waitcnt vmcnt(4)" ::: "memory"); }
    else      { asm volatile("s_waitcnt vmcnt(0)" ::: "memory"); }
    BARC();

    // ================= tile u+1 (buf1) =================
    #pragma unroll
    for (int n = 0; n < 4; ++n) b0[n] = ldB(1, n, 0);
    #pragma unroll
    for (int n = 0; n < 4; ++n) b1[n] = ldB(1, n, 1);
    #pragma unroll
    for (int m = 0; m < 4; ++m) af[m] = ldA(1, 0, m, 0);
    if (more) stA(u + 2, 0);
    BARC(); WAITL();
    MFMA16(0, b0);
    BARC();
    #pragma unroll
    for (int m = 0; m < 4; ++m) af[m] = ldA(1, 1, m, 0);
    if (more) stA(u + 2, 1);
    BARC(); WAITL();
    MFMA16(1, b0);
    BARC();
    #pragma unroll
    for (int m = 0; m < 4; ++m) af[m] = ldA(1, 0, m, 1);
    if (more) stB(u + 3, 0);
    BARC(); WAITL();
    MFMA16(0, b1);
    BARC();
    #pragma unroll
    for (int m = 0; m < 4; ++m) af[m] = ldA(1, 1, m, 1);
    if (more) stB(u + 3, 1);
    BARC(); WAITL();
    MFMA16(1, b1);
    if (more) { asm volatile("s_waitcnt vmcnt(4)" ::: "memory"); }
    BARC();
  }

  #pragma unroll
  for (int nt = 0; nt < 4; ++nt) {
    int col = bn * 256 + wn * 64 + nt * 16 + lane15;
    float bv = (bias && z0) ? bias[col] : 0.0f;
    #pragma unroll
    for (int mt = 0; mt < 8; ++mt) {
      int row0 = bm * 256 + wm * 128 + mt * 16 + quad * 4;
      #pragma unroll
      for (int r = 0; r < 4; ++r) {
        float val = acc[mt][nt][r] + bv;
        if (relu) val = fmaxf(val, 0.0f);
        if (resid && z0) val += resid[(size_t)(row0 + r) * N + col];
        store_out(&Co[(size_t)(row0 + r) * N + col], val);
      }
    }
  }
}

// ---- split-K combine (in-place): out += p1 ----------------------------
__global__ __launch_bounds__(256) void add_inplace(
    float* __restrict__ out, const float* __restrict__ p1)
{
  size_t i = ((size_t)blockIdx.x * 256 + threadIdx.x) * 4;
  float4 a = *(const float4*)(out + i);
  float4 b = *(const float4*)(p1 + i);
  *(float4*)(out + i) = make_float4(a.x + b.x, a.y + b.y, a.z + b.z, a.w + b.w);
}

// -------- MFMA flash attention v5 (single-buffer, 2 blocks/CU) ---------
// Block = 128 Q rows of one head (8 waves x 16 rows, 512 threads).
// No-max softmax in log2 domain -> partials over disjoint key ranges
// combine exactly by addition.  qblk >= 8 split into two key-range halves.
// __launch_bounds__(512, 4): cap regs at 128/lane so TWO blocks co-reside
// per CU — one block's __syncthreads/stage drain overlaps the other
// block's MFMA+VALU (R5 showed intra-block dbuf pipelining gains nothing;
// the drain must be hidden by TLP, not ILP).
__global__ __launch_bounds__(512, 4) void attn_kernel(
    const unsigned short* __restrict__ qkv, const unsigned short* __restrict__ vt,
    unsigned short* __restrict__ attnb,
    float* __restrict__ opart0, float* __restrict__ opart1,
    float* __restrict__ lpart)
{
  __shared__ __align__(16) unsigned short Klds[64 * 64];   // [key][d]
  __shared__ __align__(16) unsigned short Vlds[64 * 64];   // [d][key]
  __shared__ __align__(16) unsigned short Plds[8][16 * 72];
  int tid = threadIdx.x, lane = tid & 63, widx = tid >> 6;
  int lane15 = lane & 15, quad = lane >> 4;

  int bx = blockIdx.x;
  int qblk, p, split;
  if (bx < 16) { qblk = 15 - (bx >> 1); p = bx & 1; split = 1; }
  else         { qblk = 23 - bx;        p = 0;      split = 0; }
  int ntiles = 2 * qblk + 2;
  int kt0 = (split && p) ? (qblk + 1) : 0;
  int kt1 = (split && !p) ? (qblk + 1) : ntiles;

  int bh = blockIdx.y;                   // 0..63
  int b = bh >> 4, h = bh & 15;
  int q0w = qblk * 128 + widx * 16;      // this wave's first Q row

  const float QSCALE = 0.18033688011112042f;  // 0.125 / ln(2)
  const unsigned short* qb = qkv + (size_t)(b * C_ + q0w + lane15) * 3072 + h * 64;
  bf16x8 qa0 = *(const bf16x8*)(qb + quad * 8);
  bf16x8 qa1 = *(const bf16x8*)(qb + 32 + quad * 8);
  #pragma unroll
  for (int j = 0; j < 8; ++j) {
    qa0[j] = (__bf16)((float)qa0[j] * QSCALE);
    qa1[j] = (__bf16)((float)qa1[j] * QSCALE);
  }

  float lsum[4];
  f32x4 o[4];
  #pragma unroll
  for (int r = 0; r < 4; ++r) lsum[r] = 0.0f;
  #pragma unroll
  for (int nt = 0; nt < 4; ++nt) o[nt] = 0.0f;

  int sr = tid >> 3, sc = tid & 7, sw = sr & 7;
  const unsigned short* kg = qkv + (size_t)(b * C_ + kt0 * 64 + sr) * 3072 + 1024 + h * 64 + (sc ^ sw) * 8;
  const unsigned short* vg = vt + (size_t)bh * 64 * 2048 + (size_t)sr * 2048 + (sc ^ sw) * 8 + kt0 * 64;
  unsigned short* kl = &Klds[sr * 64 + sc * 8];
  unsigned short* vl = &Vlds[sr * 64 + sc * 8];
  int swr = lane15 & 7;

  for (int kt = kt0; kt < kt1; ++kt) {
    int k0 = kt * 64;
    async16(kg, kl);
    async16(vg, vl);
    kg += (size_t)64 * 3072;
    vg += 64;
    __syncthreads();

    if (k0 <= q0w + 15) {
      f32x4 s[4];
      #pragma unroll
      for (int g = 0; g < 4; ++g) s[g] = 0.0f;
      #pragma unroll
      for (int g = 0; g < 4; ++g) {
        int row = g * 16 + lane15;
        bf16x8 kf0 = *(const bf16x8*)&Klds[row * 64 + ((quad ^ swr) * 8)];
        bf16x8 kf1 = *(const bf16x8*)&Klds[row * 64 + (((4 + quad) ^ swr) * 8)];
        s[g] = __builtin_amdgcn_mfma_f32_16x16x32_bf16(qa0, kf0, s[g], 0, 0, 0);
        s[g] = __builtin_amdgcn_mfma_f32_16x16x32_bf16(qa1, kf1, s[g], 0, 0, 0);
      }

      if (k0 + 63 > q0w) {
        #pragma unroll
        for (int g = 0; g < 4; ++g)
          #pragma unroll
          for (int r = 0; r < 4; ++r)
            if (k0 + g * 16 + lane15 > q0w + quad * 4 + r) s[g][r] = -3.0e38f;
      }

      float pv[4][4];
      #pragma unroll
      for (int g = 0; g < 4; ++g)
        #pragma unroll
        for (int r = 0; r < 4; ++r) pv[g][r] = exp2f(s[g][r]);
      #pragma unroll
      for (int r = 0; r < 4; ++r)
        lsum[r] += (pv[0][r] + pv[1][r]) + (pv[2][r] + pv[3][r]);

      __bf16* prow = (__bf16*)&Plds[widx][0];
      #pragma unroll
      for (int g = 0; g < 4; ++g)
        #pragma unroll
        for (int r = 0; r < 4; ++r)
          prow[(quad * 4 + r) * 72 + g * 16 + lane15] = (__bf16)pv[g][r];
      asm volatile("s_waitcnt lgkmcnt(0)" ::: "memory");
      bf16x8 pa0 = *(const bf16x8*)&Plds[widx][lane15 * 72 + quad * 8];
      bf16x8 pa1 = *(const bf16x8*)&Plds[widx][lane15 * 72 + 32 + quad * 8];

      #pragma unroll
      for (int nt = 0; nt < 4; ++nt) {
        int d = nt * 16 + lane15;
        bf16x8 vf0 = *(const bf16x8*)&Vlds[d * 64 + ((quad ^ swr) * 8)];
        bf16x8 vf1 = *(const bf16x8*)&Vlds[d * 64 + (((4 + quad) ^ swr) * 8)];
        o[nt] = __builtin_amdgcn_mfma_f32_16x16x32_bf16(pa0, vf0, o[nt], 0, 0, 0);
        o[nt] = __builtin_amdgcn_mfma_f32_16x16x32_bf16(pa1, vf1, o[nt], 0, 0, 0);
      }
    }
    __syncthreads();
  }

  #pragma unroll
  for (int off = 1; off <= 8; off <<= 1)
    #pragma unroll
    for (int r = 0; r < 4; ++r)
      lsum[r] += __shfl_xor(lsum[r], off);

  if (!split) {
    float rl[4];
    #pragma unroll
    for (int r = 0; r < 4; ++r) rl[r] = 1.0f / lsum[r];
    #pragma unroll
    for (int nt = 0; nt < 4; ++nt)
      #pragma unroll
      for (int r = 0; r < 4; ++r) {
        float val = o[nt][r] * rl[r];
        attnb[(size_t)(b * C_ + q0w + quad * 4 + r) * E_ + h * 64 + nt * 16 + lane15] = f2b(val);
      }
  } else {
    float* op = p ? opart1 : opart0;
    size_t rbase = (size_t)bh * 1024 + (q0w - 1024) + quad * 4;
    #pragma unroll
    for (int nt = 0; nt < 4; ++nt)
      #pragma unroll
      for (int r = 0; r < 4; ++r)
        op[(rbase + r) * 64 + nt * 16 + lane15] = o[nt][r];
    if (lane15 == 0) {
      float* lp = lpart + (size_t)p * 65536;
      #pragma unroll
      for (int r = 0; r < 4; ++r) lp[rbase + r] = lsum[r];
    }
  }
}

// combine split-attention partials: attnb = (O0+O1)/(l0+l1) for rows 1024+
__global__ __launch_bounds__(256) void attn_combine(
    const float* __restrict__ opart0, const float* __restrict__ opart1,
    const float* __restrict__ lpart, unsigned short* __restrict__ attnb)
{
  size_t i = (size_t)blockIdx.x * 256 + threadIdx.x;  // over 64*1024*64
  int d = (int)(i & 63);
  size_t rowi = i >> 6;                 // bh*1024 + row
  int bh = (int)(rowi >> 10), row = (int)(rowi & 1023);
  float ov = opart0[rowi * 64 + d] + opart1[rowi * 64 + d];
  float lv = lpart[rowi] + lpart[65536 + rowi];
  int b = bh >> 4, h = bh & 15;
  attnb[(size_t)(b * C_ + 1024 + row) * E_ + h * 64 + d] = f2b(ov / lv);
}

// ---------------------------- launcher ---------------------------------
extern "C" void kernel_launch(void* const* d_in, const int* in_sizes, int n_in,
                              void* d_out, int out_size, void* d_ws, size_t ws_size,
                              hipStream_t stream)
{
  const float* x   = (const float*)d_in[0];
  const float* Wq  = (const float*)d_in[1];
  const float* bq  = (const float*)d_in[2];
  const float* Wk  = (const float*)d_in[3];
  const float* bk  = (const float*)d_in[4];
  const float* Wv  = (const float*)d_in[5];
  const float* bv  = (const float*)d_in[6];
  const float* g1  = (const float*)d_in[7];
  const float* be1 = (const float*)d_in[8];
  const float* g2  = (const float*)d_in[9];
  const float* be2 = (const float*)d_in[10];
  const float* W1  = (const float*)d_in[11];
  const float* bm1 = (const float*)d_in[12];
  const float* W2  = (const float*)d_in[13];
  const float* bm2 = (const float*)d_in[14];

  char* ws = (char*)d_ws;
  // Region lifetime plan:
  //  [0,16M)      norm1 (LN1 out, dead after QKV gemm) -> lpart during attn
  //               -> norm2 (LN2 out)
  //  [123.7M,+32M) free during attn -> opart1 -> out1 (LN2)
  //  [165.7M,+32M) free during attn -> opart0 -> part1 (MLP2 z1)
  unsigned short* norm1 = (unsigned short*)(ws + 0);          // 16 MB bf16 (reused as norm2)
  unsigned short* wT    = (unsigned short*)(ws + 16777216);   // 6 MB  bf16 WqkvT [3072][1024]
  unsigned short* w1T   = (unsigned short*)(ws + 23068672);   // 8 MB  bf16 [4096][1024]
  float*          biasq = (float*)(ws + 39845888);            // 12 KB fp32 [3072]
  unsigned short* qkv   = (unsigned short*)(ws + 39858176);   // 48 MB bf16 [8192][3072]
  unsigned short* vtb   = (unsigned short*)(ws + 90189824);   // 16 MB bf16 [64][64][2048]
  unsigned short* mid   = (unsigned short*)(ws + 39858176);   // 64 MB bf16 [8192][4096] (aliases qkv+vtb)
  unsigned short* attnb = (unsigned short*)(ws + 106967040);  // 16 MB bf16 [8192][1024]
  float*          out1  = (float*)(ws + 123744256);           // 32 MB fp32 [8192][1024]
  unsigned short* w2T   = (unsigned short*)(ws + 157298688);  // 8 MB  bf16 [1024][4096]
  float*          part1 = (float*)(ws + 165687296);           // 32 MB fp32 [8192][1024]
  // attn split partials (dead-region overlays, see plan above):
  float*          opart0 = (float*)(ws + 165687296);          // 16.78 MB
  float*          opart1 = (float*)(ws + 123744256);          // 16.78 MB
  float*          lpartb = (float*)(ws + 0);                  // 0.5 MB
  // total: 199,241,728 bytes
  float*          outf  = (float*)d_out;
  // MLP2 z-offset: z0 writes d_out directly, z1 writes part1.
  // (flat-address delta; wrap-safe under modular pointer arithmetic)
  size_t out_zs = (size_t)((char*)part1 - (char*)d_out) / 4;

  // weight transposes (+fp32->bf16 convert) -> [N][K]
  transpose64<float><<<dim3(16, 16, 1), 256, 0, stream>>>(Wq, wT,               1024, 1024, 1, 0, 0, 0);
  transpose64<float><<<dim3(16, 16, 1), 256, 0, stream>>>(Wk, wT + 1024 * 1024, 1024, 1024, 1, 0, 0, 0);
  transpose64<float><<<dim3(16, 16, 1), 256, 0, stream>>>(Wv, wT + 2048 * 1024, 1024, 1024, 1, 0, 0, 0);
  transpose64<float><<<dim3(64, 16, 1), 256, 0, stream>>>(W1, w1T, 4096, 1024, 1, 0, 0, 0);
  transpose64<float><<<dim3(16, 64, 1), 256, 0, stream>>>(W2, w2T, 1024, 4096, 1, 0, 0, 0);
  concat_bias<<<12, 256, 0, stream>>>(bq, bk, bv, biasq);

  // LN1: norm1 = LN(x) in bf16
  ln_kernel<<<ROWS_, 256, 0, stream>>>(x, nullptr, g1, be1, norm1, nullptr);

  // fused QKV GEMM: [8192][1024] @ [3072][1024]^T -> [8192][3072] bf16
  gemm256<unsigned short><<<dim3(384, 1, 1), 512, 0, stream>>>(
      norm1, wT, biasq, nullptr, qkv, 8192, 3072, 1024, 1024, 1024, 0, 0);

  // V^T per head: vt[b*H+h][d][c]
  transpose64<unsigned short><<<dim3(1, 32, 64), 256, 0, stream>>>(
      qkv + 2048, vtb, 3072, 2048, 16, (long)C_ * 3072, 64, (long)64 * 2048);

  // causal flash attention v5 (split heavy qblks; 2 blocks/CU)
  attn_kernel<<<dim3(24, 64), 512, 0, stream>>>(qkv, vtb, attnb, opart0, opart1, lpartb);
  attn_combine<<<16384, 256, 0, stream>>>(opart0, opart1, lpartb, attnb);

  // out1 = x + attn (fp32) ; norm2 = LN(out1) bf16
  ln_kernel<<<ROWS_, 256, 0, stream>>>(x, attnb, g2, be2, norm1, out1);

  // MLP1: relu(norm2 @ W1^T + bm1) -> mid bf16  (grid 32x16 = 512)
  gemm256<unsigned short><<<dim3(512, 1, 1), 512, 0, stream>>>(
      norm1, w1T, bm1, nullptr, mid, 8192, 4096, 1024, 1024, 1024, 1, 0);

  // MLP2 split-K: z=0 writes d_out directly (bm2 + out1 folded),
  // z=1 raw partial -> part1 (grid 32x4 x2)
  gemm256<float><<<dim3(128, 1, 2), 512, 0, stream>>>(
      mid, w2T, bm2, out1, outf, 8192, 1024, 2048, 4096, 4096, 0, out_zs);
  // out += part1
  add_inplace<<<8192, 256, 0, stream>>>(outf, part1);
}

// Round 8
// 536.261 us; speedup vs baseline: 1.0713x; 1.0564x over previous
//
#include <hip/hip_runtime.h>
#include <math.h>

#define B_ 4
#define C_ 2048
#define E_ 1024
#define H_ 16
#define D_ 64
#define ROWS_ (B_*C_)   // 8192

typedef __bf16 bf16x8 __attribute__((ext_vector_type(8)));
typedef float f32x4 __attribute__((ext_vector_type(4)));

__device__ __forceinline__ float b2f(unsigned short u) {
  unsigned int x = ((unsigned int)u) << 16;
  return __builtin_bit_cast(float, x);
}
__device__ __forceinline__ unsigned short f2b(float f) {
  unsigned int x = __builtin_bit_cast(unsigned int, f);
  unsigned int r = (x + 0x7FFFu + ((x >> 16) & 1u)) >> 16;
  return (unsigned short)r;
}
__device__ __forceinline__ unsigned short tob(float f) { return f2b(f); }
__device__ __forceinline__ unsigned short tob(unsigned short u) { return u; }
__device__ __forceinline__ void store_out(float* p, float v) { *p = v; }
__device__ __forceinline__ void store_out(unsigned short* p, float v) { *p = f2b(v); }

__device__ __forceinline__ void async16(const void* g, void* l) {
  __builtin_amdgcn_global_load_lds(
      (__attribute__((address_space(1))) unsigned int*)g,
      (__attribute__((address_space(3))) unsigned int*)l, 16, 0, 0);
}

// ------------- 64x64 tiled transpose, InT -> bf16 ----------------------
template <typename InT>
__global__ __launch_bounds__(256) void transpose64(
    const InT* __restrict__ in, unsigned short* __restrict__ out,
    int s_in, int s_out, int Hz, long zs_b, long zs_h, long zs_out)
{
  __shared__ unsigned short t[64][65];
  int z = blockIdx.z;
  long ib = (long)(z / Hz) * zs_b + (long)(z % Hz) * zs_h;
  long ob = (long)z * zs_out;
  int r0 = blockIdx.y * 64, c0 = blockIdx.x * 64;
  int lane = threadIdx.x & 63, grp = threadIdx.x >> 6;
  for (int i = grp; i < 64; i += 4)
    t[i][lane] = tob(in[ib + (long)(r0 + i) * s_in + c0 + lane]);
  __syncthreads();
  for (int i = grp; i < 64; i += 4)
    out[ob + (long)(c0 + i) * s_out + r0 + lane] = t[lane][i];
}

__global__ void concat_bias(const float* __restrict__ q,
                            const float* __restrict__ k,
                            const float* __restrict__ v,
                            float* __restrict__ o)
{
  int i = blockIdx.x * 256 + threadIdx.x;  // 3072 total
  o[i] = (i < 1024) ? q[i] : (i < 2048) ? k[i - 1024] : v[i - 2048];
}

// ---------------- LayerNorm (optionally fused residual add) ------------
__global__ __launch_bounds__(256) void ln_kernel(
    const float* __restrict__ xin, const unsigned short* __restrict__ addend,
    const float* __restrict__ g, const float* __restrict__ beta,
    unsigned short* __restrict__ yout, float* __restrict__ out1)
{
  int row = blockIdx.x, tid = threadIdx.x;
  size_t base = (size_t)row * E_ + tid * 4;
  float4 xa = *(const float4*)(xin + base);
  float v0 = xa.x, v1 = xa.y, v2 = xa.z, v3 = xa.w;
  if (addend) {
    ushort4 aa = *(const ushort4*)(addend + base);
    v0 += b2f(aa.x); v1 += b2f(aa.y); v2 += b2f(aa.z); v3 += b2f(aa.w);
  }
  if (out1) {
    *(float4*)(out1 + base) = make_float4(v0, v1, v2, v3);
  }
  float s = v0 + v1 + v2 + v3;
  float sq = v0*v0 + v1*v1 + v2*v2 + v3*v3;
  #pragma unroll
  for (int off = 32; off >= 1; off >>= 1) {
    s  += __shfl_xor(s, off);
    sq += __shfl_xor(sq, off);
  }
  __shared__ float red[8];
  int wid = tid >> 6;
  if ((tid & 63) == 0) { red[wid] = s; red[4 + wid] = sq; }
  __syncthreads();
  s  = red[0] + red[1] + red[2] + red[3];
  sq = red[4] + red[5] + red[6] + red[7];
  float mu = s * (1.0f / E_);
  float var = sq * (1.0f / E_) - mu * mu;
  float rs = rsqrtf(var + 1e-5f);
  float4 ga = *(const float4*)(g + tid * 4);
  float4 ba = *(const float4*)(beta + tid * 4);
  ushort4 o;
  o.x = f2b((v0 - mu) * rs * ga.x + ba.x);
  o.y = f2b((v1 - mu) * rs * ga.y + ba.y);
  o.z = f2b((v2 - mu) * rs * ga.z + ba.z);
  o.w = f2b((v3 - mu) * rs * ga.w + ba.w);
  *(ushort4*)(yout + base) = o;
}

// ------- bf16 GEMM v2: BK=64, XOR-swizzled LDS, XCD-aware mapping ------
// C = A @ Bt^T (+bias) (+relu) (+resid).  bias/resid applied only on z==0
// (split-K partials from z>0 are raw).  [R0-verified best structure:
// 5 alternative schedules all measured equal-or-worse; frozen.]
template <typename OutT>
__global__ __launch_bounds__(256) void gemm_bt(
    const unsigned short* __restrict__ A, const unsigned short* __restrict__ Bt,
    const float* __restrict__ bias, const float* __restrict__ resid,
    OutT* __restrict__ Co, int M, int N, int K, int lda, int ldb,
    int relu, size_t zs)
{
  __shared__ __align__(16) unsigned short As[128 * 64];
  __shared__ __align__(16) unsigned short Bs[128 * 64];
  int tid = threadIdx.x, lane = tid & 63, wid = tid >> 6;
  int lane15 = lane & 15, quad = lane >> 4;

  int i = blockIdx.x;
  int xcd = i & 7, s = i >> 3;
  int bn = s >> 3;                       // bn-major within XCD
  int bm = xcd * 8 + (s & 7);            // contiguous bm strip per XCD
  size_t koff = (size_t)blockIdx.z * K;
  int z0 = (blockIdx.z == 0);
  Co += (size_t)blockIdx.z * zs;

  int m_lo = (wid & 1) * 64, n_lo = (wid >> 1) * 64;

  f32x4 acc[4][4];
  #pragma unroll
  for (int a = 0; a < 4; ++a)
    #pragma unroll
    for (int bb = 0; bb < 4; ++bb) acc[a][bb] = 0.0f;

  int sr = tid >> 3, sc = tid & 7;
  int scs = (sc ^ (sr & 7)) * 8;
  const unsigned short* Ag = A + koff + (size_t)(bm * 128 + sr) * lda + scs;
  const unsigned short* Bg = Bt + koff + (size_t)(bn * 128 + sr) * ldb + scs;
  unsigned short* Al = &As[wid * 512];   // wave-uniform LDS dest
  unsigned short* Bl = &Bs[wid * 512];
  int sw15 = lane15 & 7;

  for (int k0 = 0; k0 < K; k0 += 64) {
    async16(Ag,                     Al);
    async16(Ag + (size_t)32 * lda,  Al + 32 * 64);
    async16(Ag + (size_t)64 * lda,  Al + 64 * 64);
    async16(Ag + (size_t)96 * lda,  Al + 96 * 64);
    async16(Bg,                     Bl);
    async16(Bg + (size_t)32 * ldb,  Bl + 32 * 64);
    async16(Bg + (size_t)64 * ldb,  Bl + 64 * 64);
    async16(Bg + (size_t)96 * ldb,  Bl + 96 * 64);
    Ag += 64; Bg += 64;
    __syncthreads();

    #pragma unroll
    for (int kk = 0; kk < 2; ++kk) {
      bf16x8 af[4], bfr[4];
      int qs = kk * 4 + quad;
      #pragma unroll
      for (int t = 0; t < 4; ++t)
        af[t] = *(const bf16x8*)&As[(m_lo + t * 16 + lane15) * 64 + ((qs ^ sw15) * 8)];
      #pragma unroll
      for (int t = 0; t < 4; ++t)
        bfr[t] = *(const bf16x8*)&Bs[(n_lo + t * 16 + lane15) * 64 + ((qs ^ sw15) * 8)];
      #pragma unroll
      for (int mt = 0; mt < 4; ++mt)
        #pragma unroll
        for (int nt = 0; nt < 4; ++nt)
          acc[mt][nt] = __builtin_amdgcn_mfma_f32_16x16x32_bf16(af[mt], bfr[nt], acc[mt][nt], 0, 0, 0);
    }
    __syncthreads();
  }

  #pragma unroll
  for (int nt = 0; nt < 4; ++nt) {
    int col = bn * 128 + n_lo + nt * 16 + lane15;
    float bv = (bias && z0) ? bias[col] : 0.0f;
    #pragma unroll
    for (int mt = 0; mt < 4; ++mt) {
      int row0 = bm * 128 + m_lo + mt * 16 + quad * 4;
      #pragma unroll
      for (int r = 0; r < 4; ++r) {
        float val = acc[mt][nt][r] + bv;
        if (relu) val = fmaxf(val, 0.0f);
        if (resid && z0) val += resid[(size_t)(row0 + r) * N + col];
        store_out(&Co[(size_t)(row0 + r) * N + col], val);
      }
    }
  }
}

// -------- MFMA flash attention v5 (v3 + causal key-range split) --------
// Block = 128 Q rows of one head (8 waves x 16 rows, 512 threads).
// No-max softmax in log2 domain -> partials over disjoint key ranges
// combine exactly by addition.  qblk >= 8 is split into two key-range
// halves (each <= 16 tiles, balancing the causal load); partial O (fp32)
// and l go to scratch, combined by attn_combine.
// blockIdx.x decode: bx<16 -> qblk=15-(bx>>1), half p=bx&1 (split);
//                    bx>=16 -> qblk=23-bx (unsplit).
__global__ __launch_bounds__(512) void attn_kernel(
    const unsigned short* __restrict__ qkv, const unsigned short* __restrict__ vt,
    unsigned short* __restrict__ attnb,
    float* __restrict__ opart0, float* __restrict__ opart1,
    float* __restrict__ lpart)
{
  __shared__ __align__(16) unsigned short Klds[64 * 64];   // [key][d]
  __shared__ __align__(16) unsigned short Vlds[64 * 64];   // [d][key]
  __shared__ __align__(16) unsigned short Plds[8][16 * 72];
  int tid = threadIdx.x, lane = tid & 63, widx = tid >> 6;
  int lane15 = lane & 15, quad = lane >> 4;

  int bx = blockIdx.x;
  int qblk, p, split;
  if (bx < 16) { qblk = 15 - (bx >> 1); p = bx & 1; split = 1; }
  else         { qblk = 23 - bx;        p = 0;      split = 0; }
  int ntiles = 2 * qblk + 2;
  int kt0 = (split && p) ? (qblk + 1) : 0;
  int kt1 = (split && !p) ? (qblk + 1) : ntiles;

  int bh = blockIdx.y;                   // 0..63
  int b = bh >> 4, h = bh & 15;
  int q0w = qblk * 128 + widx * 16;      // this wave's first Q row

  const float QSCALE = 0.18033688011112042f;  // 0.125 / ln(2)
  const unsigned short* qb = qkv + (size_t)(b * C_ + q0w + lane15) * 3072 + h * 64;
  bf16x8 qa0 = *(const bf16x8*)(qb + quad * 8);
  bf16x8 qa1 = *(const bf16x8*)(qb + 32 + quad * 8);
  #pragma unroll
  for (int j = 0; j < 8; ++j) {
    qa0[j] = (__bf16)((float)qa0[j] * QSCALE);
    qa1[j] = (__bf16)((float)qa1[j] * QSCALE);
  }

  float lsum[4];
  f32x4 o[4];
  #pragma unroll
  for (int r = 0; r < 4; ++r) lsum[r] = 0.0f;
  #pragma unroll
  for (int nt = 0; nt < 4; ++nt) o[nt] = 0.0f;

  int sr = tid >> 3, sc = tid & 7, sw = sr & 7;
  const unsigned short* kg = qkv + (size_t)(b * C_ + kt0 * 64 + sr) * 3072 + 1024 + h * 64 + (sc ^ sw) * 8;
  const unsigned short* vg = vt + (size_t)bh * 64 * 2048 + (size_t)sr * 2048 + (sc ^ sw) * 8 + kt0 * 64;
  unsigned short* kl = &Klds[sr * 64 + sc * 8];
  unsigned short* vl = &Vlds[sr * 64 + sc * 8];
  int swr = lane15 & 7;

  for (int kt = kt0; kt < kt1; ++kt) {
    int k0 = kt * 64;
    async16(kg, kl);
    async16(vg, vl);
    kg += (size_t)64 * 3072;
    vg += 64;
    __syncthreads();

    if (k0 <= q0w + 15) {
      f32x4 s[4];
      #pragma unroll
      for (int g = 0; g < 4; ++g) s[g] = 0.0f;
      #pragma unroll
      for (int g = 0; g < 4; ++g) {
        int row = g * 16 + lane15;
        bf16x8 kf0 = *(const bf16x8*)&Klds[row * 64 + ((quad ^ swr) * 8)];
        bf16x8 kf1 = *(const bf16x8*)&Klds[row * 64 + (((4 + quad) ^ swr) * 8)];
        s[g] = __builtin_amdgcn_mfma_f32_16x16x32_bf16(qa0, kf0, s[g], 0, 0, 0);
        s[g] = __builtin_amdgcn_mfma_f32_16x16x32_bf16(qa1, kf1, s[g], 0, 0, 0);
      }

      if (k0 + 63 > q0w) {
        #pragma unroll
        for (int g = 0; g < 4; ++g)
          #pragma unroll
          for (int r = 0; r < 4; ++r)
            if (k0 + g * 16 + lane15 > q0w + quad * 4 + r) s[g][r] = -3.0e38f;
      }

      float pv[4][4];
      #pragma unroll
      for (int g = 0; g < 4; ++g)
        #pragma unroll
        for (int r = 0; r < 4; ++r) pv[g][r] = exp2f(s[g][r]);
      #pragma unroll
      for (int r = 0; r < 4; ++r)
        lsum[r] += (pv[0][r] + pv[1][r]) + (pv[2][r] + pv[3][r]);

      __bf16* prow = (__bf16*)&Plds[widx][0];
      #pragma unroll
      for (int g = 0; g < 4; ++g)
        #pragma unroll
        for (int r = 0; r < 4; ++r)
          prow[(quad * 4 + r) * 72 + g * 16 + lane15] = (__bf16)pv[g][r];
      asm volatile("s_waitcnt lgkmcnt(0)" ::: "memory");
      bf16x8 pa0 = *(const bf16x8*)&Plds[widx][lane15 * 72 + quad * 8];
      bf16x8 pa1 = *(const bf16x8*)&Plds[widx][lane15 * 72 + 32 + quad * 8];

      #pragma unroll
      for (int nt = 0; nt < 4; ++nt) {
        int d = nt * 16 + lane15;
        bf16x8 vf0 = *(const bf16x8*)&Vlds[d * 64 + ((quad ^ swr) * 8)];
        bf16x8 vf1 = *(const bf16x8*)&Vlds[d * 64 + (((4 + quad) ^ swr) * 8)];
        o[nt] = __builtin_amdgcn_mfma_f32_16x16x32_bf16(pa0, vf0, o[nt], 0, 0, 0);
        o[nt] = __builtin_amdgcn_mfma_f32_16x16x32_bf16(pa1, vf1, o[nt], 0, 0, 0);
      }
    }
    __syncthreads();
  }

  #pragma unroll
  for (int off = 1; off <= 8; off <<= 1)
    #pragma unroll
    for (int r = 0; r < 4; ++r)
      lsum[r] += __shfl_xor(lsum[r], off);

  if (!split) {
    float rl[4];
    #pragma unroll
    for (int r = 0; r < 4; ++r) rl[r] = 1.0f / lsum[r];
    #pragma unroll
    for (int nt = 0; nt < 4; ++nt)
      #pragma unroll
      for (int r = 0; r < 4; ++r) {
        float val = o[nt][r] * rl[r];
        attnb[(size_t)(b * C_ + q0w + quad * 4 + r) * E_ + h * 64 + nt * 16 + lane15] = f2b(val);
      }
  } else {
    float* op = p ? opart1 : opart0;
    size_t rbase = (size_t)bh * 1024 + (q0w - 1024) + quad * 4;
    #pragma unroll
    for (int nt = 0; nt < 4; ++nt)
      #pragma unroll
      for (int r = 0; r < 4; ++r)
        op[(rbase + r) * 64 + nt * 16 + lane15] = o[nt][r];
    if (lane15 == 0) {
      float* lp = lpart + (size_t)p * 65536;
      #pragma unroll
      for (int r = 0; r < 4; ++r) lp[rbase + r] = lsum[r];
    }
  }
}

// combine split-attention partials: attnb = (O0+O1)/(l0+l1) for rows 1024+
__global__ __launch_bounds__(256) void attn_combine(
    const float* __restrict__ opart0, const float* __restrict__ opart1,
    const float* __restrict__ lpart, unsigned short* __restrict__ attnb)
{
  size_t i = (size_t)blockIdx.x * 256 + threadIdx.x;  // over 64*1024*64
  int d = (int)(i & 63);
  size_t rowi = i >> 6;                 // bh*1024 + row
  int bh = (int)(rowi >> 10), row = (int)(rowi & 1023);
  float ov = opart0[rowi * 64 + d] + opart1[rowi * 64 + d];
  float lv = lpart[rowi] + lpart[65536 + rowi];
  int b = bh >> 4, h = bh & 15;
  attnb[(size_t)(b * C_ + 1024 + row) * E_ + h * 64 + d] = f2b(ov / lv);
}

// ---------------------------- launcher ---------------------------------
extern "C" void kernel_launch(void* const* d_in, const int* in_sizes, int n_in,
                              void* d_out, int out_size, void* d_ws, size_t ws_size,
                              hipStream_t stream)
{
  const float* x   = (const float*)d_in[0];
  const float* Wq  = (const float*)d_in[1];
  const float* bq  = (const float*)d_in[2];
  const float* Wk  = (const float*)d_in[3];
  const float* bk  = (const float*)d_in[4];
  const float* Wv  = (const float*)d_in[5];
  const float* bv  = (const float*)d_in[6];
  const float* g1  = (const float*)d_in[7];
  const float* be1 = (const float*)d_in[8];
  const float* g2  = (const float*)d_in[9];
  const float* be2 = (const float*)d_in[10];
  const float* W1  = (const float*)d_in[11];
  const float* bm1 = (const float*)d_in[12];
  const float* W2  = (const float*)d_in[13];
  const float* bm2 = (const float*)d_in[14];

  char* ws = (char*)d_ws;
  // Region lifetime plan:
  //  [0,16M)      norm1 (LN1 out, dead after QKV gemm) -> lpart during attn
  //               -> norm2 (LN2 out)
  //  [123.7M,+32M) free during attn -> opart1 -> out1 (LN2)
  //  [165.7M,+32M) free during attn -> opart0 (dead after attn_combine)
  unsigned short* norm1 = (unsigned short*)(ws + 0);          // 16 MB bf16 (reused as norm2)
  unsigned short* wT    = (unsigned short*)(ws + 16777216);   // 6 MB  bf16 WqkvT [3072][1024]
  unsigned short* w1T   = (unsigned short*)(ws + 23068672);   // 8 MB  bf16 [4096][1024]
  float*          biasq = (float*)(ws + 39845888);            // 12 KB fp32 [3072]
  unsigned short* qkv   = (unsigned short*)(ws + 39858176);   // 48 MB bf16 [8192][3072]
  unsigned short* vtb   = (unsigned short*)(ws + 90189824);   // 16 MB bf16 [64][64][2048]
  unsigned short* mid   = (unsigned short*)(ws + 39858176);   // 64 MB bf16 [8192][4096] (aliases qkv+vtb)
  unsigned short* attnb = (unsigned short*)(ws + 106967040);  // 16 MB bf16 [8192][1024]
  float*          out1  = (float*)(ws + 123744256);           // 32 MB fp32 [8192][1024]
  unsigned short* w2T   = (unsigned short*)(ws + 157298688);  // 8 MB  bf16 [1024][4096]
  // attn split partials (dead-region overlays, see plan above):
  float*          opart0 = (float*)(ws + 165687296);          // 16.78 MB
  float*          opart1 = (float*)(ws + 123744256);          // 16.78 MB
  float*          lpartb = (float*)(ws + 0);                  // 0.5 MB
  // total: 199,241,728 bytes (unchanged footprint)

  // weight transposes (+fp32->bf16 convert) -> [N][K]
  transpose64<float><<<dim3(16, 16, 1), 256, 0, stream>>>(Wq, wT,               1024, 1024, 1, 0, 0, 0);
  transpose64<float><<<dim3(16, 16, 1), 256, 0, stream>>>(Wk, wT + 1024 * 1024, 1024, 1024, 1, 0, 0, 0);
  transpose64<float><<<dim3(16, 16, 1), 256, 0, stream>>>(Wv, wT + 2048 * 1024, 1024, 1024, 1, 0, 0, 0);
  transpose64<float><<<dim3(64, 16, 1), 256, 0, stream>>>(W1, w1T, 4096, 1024, 1, 0, 0, 0);
  transpose64<float><<<dim3(16, 64, 1), 256, 0, stream>>>(W2, w2T, 1024, 4096, 1, 0, 0, 0);
  concat_bias<<<12, 256, 0, stream>>>(bq, bk, bv, biasq);

  // LN1: norm1 = LN(x) in bf16
  ln_kernel<<<ROWS_, 256, 0, stream>>>(x, nullptr, g1, be1, norm1, nullptr);

  // fused QKV GEMM: [8192][1024] @ [3072][1024]^T -> [8192][3072] bf16
  gemm_bt<unsigned short><<<dim3(24 * 64, 1, 1), 256, 0, stream>>>(
      norm1, wT, biasq, nullptr, qkv, 8192, 3072, 1024, 1024, 1024, 0, 0);

  // V^T per head: vt[b*H+h][d][c]
  transpose64<unsigned short><<<dim3(1, 32, 64), 256, 0, stream>>>(
      qkv + 2048, vtb, 3072, 2048, 16, (long)C_ * 3072, 64, (long)64 * 2048);

  // causal flash attention v5 (split heavy qblks)
  attn_kernel<<<dim3(24, 64), 512, 0, stream>>>(qkv, vtb, attnb, opart0, opart1, lpartb);
  attn_combine<<<16384, 256, 0, stream>>>(opart0, opart1, lpartb, attnb);

  // out1 = x + attn (fp32) ; norm2 = LN(out1) bf16
  ln_kernel<<<ROWS_, 256, 0, stream>>>(x, attnb, g2, be2, norm1, out1);

  // MLP1: relu(norm2 @ W1^T + bm1) -> mid bf16
  gemm_bt<unsigned short><<<dim3(32 * 64, 1, 1), 256, 0, stream>>>(
      norm1, w1T, bm1, nullptr, mid, 8192, 4096, 1024, 1024, 1024, 1, 0);

  // MLP2 single-pass (was split-K x2 + add2 = 128 MB extra epilogue
  // traffic): K=4096, bias+residual folded, writes d_out directly.
  gemm_bt<float><<<dim3(8 * 64, 1, 1), 256, 0, stream>>>(
      mid, w2T, bm2, out1, (float*)d_out, 8192, 1024, 4096, 4096, 4096, 0, 0);
}